// Round 4
// baseline (279.844 us; speedup 1.0000x reference)
//
#include <hip/hip_runtime.h>
#include <cstdint>
#include <cstddef>

// VQ-VAE quantization forward, MI355X/gfx950 — bf16 split MFMA, pipelined staging.
// dot(x,e_norm) = xh*eh + xh*el + xl*eh (3x mfma_f32_16x16x32_bf16, fp32 accum).

typedef __attribute__((ext_vector_type(8))) short short8;
typedef __attribute__((ext_vector_type(4))) float f32x4;

namespace {
constexpr int kNT = 25600;
constexpr int kD  = 1024;
constexpr int kM  = 256;
constexpr size_t kQElems = (size_t)kNT * kD;

// ws layout (float units). imgC: 32 chunks x 32KB, chunk = [img(16KB)][n(64B)][sub16B]
// phys sub-block s stores logical k-sub (s ^ ...) baked at generation; see vq_normalize.
constexpr int WS_E2N  = 262144;   // ||e_norm||^2 (256)
constexpr int WS_SCL  = 262400;   // ||e_raw||+1e-4 (256)
constexpr int WS_E2R  = 262656;   // ||e_raw||^2 (256)
constexpr int WS_COM  = 262912;   // commitment accumulator (1)
constexpr int WS_HIST = 262916;   // histogram (256 int)
}

typedef __attribute__((address_space(3))) unsigned int        lds_u32;
typedef const __attribute__((address_space(1))) unsigned int  glb_u32;

__device__ __forceinline__ void gl2lds16(const void* g, void* l) {
  __builtin_amdgcn_global_load_lds((glb_u32*)g, (lds_u32*)l, 16, 0, 0);
}

// ---------------- kernel 1: normalize codebook -> chunk-major swizzled bf16 hi/lo ----
__global__ __launch_bounds__(256) void vq_normalize(const float* __restrict__ emb,
                                                    float* __restrict__ ws) {
  const int m = blockIdx.x, t = threadIdx.x;
  __shared__ float rowS[1024];
  __shared__ float red[4];
  const float4 v = reinterpret_cast<const float4*>(emb + (size_t)m * kD)[t];
  reinterpret_cast<float4*>(rowS)[t] = v;
  float s = v.x * v.x + v.y * v.y + v.z * v.z + v.w * v.w;
#pragma unroll
  for (int mask = 32; mask >= 1; mask >>= 1) s += __shfl_xor(s, mask);
  if ((t & 63) == 0) red[t >> 6] = s;
  __syncthreads();                    // covers rowS + red
  const float tot = red[0] + red[1] + red[2] + red[3];
  const float sc  = sqrtf(tot) + 1e-4f;
  const float inv = 1.0f / sc;
  if (t == 0) {
    ws[WS_E2N + m] = tot * inv * inv;
    ws[WS_SCL + m] = sc;
    ws[WS_E2R + m] = tot;
  }
  if (m == 0) {                       // fold the memset in
    ((int*)(ws + WS_HIST))[t] = 0;
    if (t == 0) ws[WS_COM] = 0.0f;
  }
  // pass B: thread t -> img = t>>7, 8 consecutive k at j*8, j = t&127
  const int img = t >> 7, j = t & 127;
  const int c = j >> 2, qq = j & 3, ps = qq ^ (m & 3);   // read-side bank swizzle
  unsigned int pk[4];
#pragma unroll
  for (int i = 0; i < 4; ++i) {
    unsigned int two[2];
#pragma unroll
    for (int e = 0; e < 2; ++e) {
      const float f = rowS[j * 8 + 2 * i + e] * inv;
      const unsigned int b = __float_as_uint(f);
      unsigned short u;
      if (img == 0) {
        u = (unsigned short)(b >> 16);
      } else {
        const float lof = f - __uint_as_float(b & 0xFFFF0000u);
        u = (unsigned short)(__float_as_uint(lof) >> 16);
      }
      two[e] = u;
    }
    pk[i] = two[0] | (two[1] << 16);
  }
  char* dst = (char*)ws + (size_t)c * 32768 + img * 16384 + m * 64 + ps * 16;
  *(uint4*)dst = make_uint4(pk[0], pk[1], pk[2], pk[3]);
}

// ---------------- kernel 2: MFMA distances + argmin + gather + stats ----------------
// 800 blocks x 256 thr. Wave w: rw=w&1 (16-row half), ch=w>>1 (128-col half).
__global__ __launch_bounds__(256, 3) void vq_main(const float* __restrict__ x,
                                                  const float* __restrict__ emb,
                                                  const float* __restrict__ wsc,
                                                  float* __restrict__ out,
                                                  float* __restrict__ commit_sum,
                                                  int* __restrict__ hist) {
  __shared__ unsigned short Bs[2][8192];   // 32 KB: [img][n*32 + swizzled k-sub]
  __shared__ float Xs[1024];               // 4 KB: [row(128B)][swizzled 16B subs]
  __shared__ float e2n_s[256];
  __shared__ float candv[2][32];
  __shared__ int   candj[2][32];
  __shared__ float x2s[32];
  __shared__ int   idx_s[32];

  const int t = threadIdx.x, l = t & 63, w = t >> 6;
  const int rw = w & 1, ch = w >> 1;
  const int q = l >> 4, nlo = l & 15;
  const int r0 = blockIdx.x * 32;

  e2n_s[t] = wsc[WS_E2N + t];

  const char* imgC = (const char*)wsc;
  // X staging: thread t -> row xr=t>>3, phys slot xs=t&7 holds global sub xs^(xr&7)
  const int xr = t >> 3, xsl = t & 7, xu = xsl ^ (xr & 7);
  const float* xsrc = x + (size_t)(r0 + xr) * kD + xu * 4;   // + cc*32
  char* bdst = (char*)Bs + w * 1024;                          // wave-uniform LDS bases
  char* xdst = (char*)Xs + w * 1024;
  const char* bsrc = imgC + w * 1024 + l * 16;                // + cc*32768 + it*4096

  // stage chunk 0
#pragma unroll
  for (int it = 0; it < 8; ++it) gl2lds16(bsrc + it * 4096, bdst + it * 4096);
  gl2lds16(xsrc, xdst);

  f32x4 acc[8];
#pragma unroll
  for (int ct = 0; ct < 8; ++ct) acc[ct] = (f32x4)0.0f;
  float x2 = 0.0f;

  const int ar   = rw * 16 + nlo;                 // A row for this lane
  const float* xrow = &Xs[ar * 32];
  const int sub0 = ((2 * q)     ^ (ar & 7)) * 4;  // logical sub 2q, 2q+1 (8 f32)
  const int sub1 = ((2 * q + 1) ^ (ar & 7)) * 4;

#pragma unroll 1
  for (int cc = 0; cc < 32; ++cc) {
    __syncthreads();                               // chunk cc staged (drains vmcnt)
    const float4 fa = *(const float4*)(xrow + sub0);
    const float4 fb = *(const float4*)(xrow + sub1);
    short8 bh[8], bl[8];
#pragma unroll
    for (int ct = 0; ct < 8; ++ct) {
      const int n = ch * 128 + ct * 16 + nlo;
      const int off = n * 32 + (q ^ (n & 3)) * 8;
      bh[ct] = *(const short8*)&Bs[0][off];
      bl[ct] = *(const short8*)&Bs[1][off];
    }
    union { short8 v; unsigned short u[8]; } AH, AL;
#pragma unroll
    for (int jj = 0; jj < 8; ++jj) {
      const float fv = (jj < 4) ? (&fa.x)[jj] : (&fb.x)[jj - 4];
      const unsigned int b = __float_as_uint(fv);
      AH.u[jj] = (unsigned short)(b >> 16);
      const float lof = fv - __uint_as_float(b & 0xFFFF0000u);
      AL.u[jj] = (unsigned short)(__float_as_uint(lof) >> 16);
      x2 += fv * fv;
    }
    __syncthreads();                               // all LDS reads of cc done
    if (cc < 31) {                                 // issue cc+1; drains during MFMAs
      const char* bs2 = bsrc + (size_t)(cc + 1) * 32768;
#pragma unroll
      for (int it = 0; it < 8; ++it) gl2lds16(bs2 + it * 4096, bdst + it * 4096);
      gl2lds16(xsrc + (cc + 1) * 32, xdst);
    }
#pragma unroll
    for (int ct = 0; ct < 8; ++ct) {
      acc[ct] = __builtin_amdgcn_mfma_f32_16x16x32_bf16(AH.v, bh[ct], acc[ct], 0, 0, 0);
      acc[ct] = __builtin_amdgcn_mfma_f32_16x16x32_bf16(AH.v, bl[ct], acc[ct], 0, 0, 0);
      acc[ct] = __builtin_amdgcn_mfma_f32_16x16x32_bf16(AL.v, bh[ct], acc[ct], 0, 0, 0);
    }
  }

  // full-row ||x||^2 (combine the 4 k-quads)
  x2 += __shfl_xor(x2, 16);
  x2 += __shfl_xor(x2, 32);
  if (ch == 0 && q == 0) x2s[ar] = x2;

  // register argmin: lane holds rows q*4+reg, col j = ch*128 + ct*16 + nlo
  float bv[4]; int bj[4];
#pragma unroll
  for (int r = 0; r < 4; ++r) { bv[r] = 3.0e38f; bj[r] = 0; }
#pragma unroll
  for (int ct = 0; ct < 8; ++ct) {
    const int j = ch * 128 + ct * 16 + nlo;
    const float e2 = e2n_s[j];
#pragma unroll
    for (int r = 0; r < 4; ++r) {
      const float v = e2 - 2.0f * acc[ct][r];
      if (v < bv[r]) { bv[r] = v; bj[r] = j; }    // ct ascending -> first-min tiebreak
    }
  }
#pragma unroll
  for (int mask = 1; mask <= 8; mask <<= 1) {
#pragma unroll
    for (int r = 0; r < 4; ++r) {
      const float ov = __shfl_xor(bv[r], mask);
      const int   oj = __shfl_xor(bj[r], mask);
      if (ov < bv[r] || (ov == bv[r] && oj < bj[r])) { bv[r] = ov; bj[r] = oj; }
    }
  }
  if (nlo == 0) {
#pragma unroll
    for (int r = 0; r < 4; ++r) {
      const int row = rw * 16 + q * 4 + r;
      candv[ch][row] = bv[r];
      candj[ch][row] = bj[r];
    }
  }
  __syncthreads();

  if (t < 32) {
    float v0 = candv[0][t]; int j0 = candj[0][t];
    const float v1 = candv[1][t]; const int j1 = candj[1][t];
    if (v1 < v0) { v0 = v1; j0 = j1; }            // ties -> ch0 (smaller j)
    idx_s[t] = j0;
    atomicAdd(&hist[j0], 1);
    // ||x-e_raw||^2 = ||x||^2 + ||e_raw||^2 - (e2n - v_min)*scl   [(e2n-v)=2*dot]
    const float cl = x2s[t] + wsc[WS_E2R + j0] - (e2n_s[j0] - v0) * wsc[WS_SCL + j0];
    atomicAdd(commit_sum, cl);
  }
  __syncthreads();

  // gather: quantized row = raw embedding[argmin]
  const float4* emb4 = reinterpret_cast<const float4*>(emb);
  float4* out4 = reinterpret_cast<float4*>(out);
#pragma unroll 4
  for (int i = 0; i < 32; ++i) {
    const int mm = idx_s[i];
    out4[(size_t)(r0 + i) * (kD / 4) + t] = emb4[(size_t)mm * (kD / 4) + t];
  }
}

// ---------------- kernel 3: scalars ----------------
__global__ __launch_bounds__(256) void vq_final(const int* __restrict__ hist,
                                                const float* __restrict__ commit_sum,
                                                float* __restrict__ out) {
  const int t = threadIdx.x;
  const float p = (float)hist[t] * (1.0f / (float)kNT);
  float s = p * logf(p + 1e-10f);
#pragma unroll
  for (int mask = 32; mask >= 1; mask >>= 1) s += __shfl_xor(s, mask);
  __shared__ float red[4];
  if ((t & 63) == 0) red[t >> 6] = s;
  __syncthreads();
  if (t == 0) {
    const float ent = red[0] + red[1] + red[2] + red[3];
    out[kQElems]     = commit_sum[0] * (1.0f / (float)kQElems);
    out[kQElems + 1] = expf(-ent);
  }
}

extern "C" void kernel_launch(void* const* d_in, const int* in_sizes, int n_in,
                              void* d_out, int out_size, void* d_ws, size_t ws_size,
                              hipStream_t stream) {
  (void)in_sizes; (void)n_in; (void)out_size; (void)ws_size;
  const float* x   = (const float*)d_in[0];
  const float* emb = (const float*)d_in[1];
  float* out = (float*)d_out;
  float* ws  = (float*)d_ws;

  hipLaunchKernelGGL(vq_normalize, dim3(kM), dim3(256), 0, stream, emb, ws);
  hipLaunchKernelGGL(vq_main, dim3(kNT / 32), dim3(256), 0, stream,
                     x, emb, ws, out, ws + WS_COM, (int*)(ws + WS_HIST));
  hipLaunchKernelGGL(vq_final, dim3(1), dim3(256), 0, stream,
                     (const int*)(ws + WS_HIST), ws + WS_COM, out);
}